// Round 6
// baseline (50.070 us; speedup 1.0000x reference)
//
#include <hip/hip_runtime.h>

// Problem constants (from reference)
#define C       256      // C_IN == C_OUT
#define KTOP    16.0f
#define NITER   50
#define BATCH   8
#define LENGTH  16384
#define L4N     (LENGTH / 4)      // 4096 float4 per row
#define NROWS   (BATCH * C)       // 2048 rows
#define TOTAL4  (NROWS * L4N)     // 8,388,608 float4
#define NBLOCKS (TOTAL4 / 1024)   // 1024 float4 per 256-thread block -> 8192

// native 4-float vector (works with __builtin_nontemporal_store)
typedef float f4 __attribute__((ext_vector_type(4)));

// ---------------------------------------------------------------------------
// Wave-wide (64-lane) float sum via DPP — pure VALU, no LDS, no waitcnt.
// ---------------------------------------------------------------------------
__device__ __forceinline__ float wave_sum_dpp(float x) {
    float t;
    t = __int_as_float(__builtin_amdgcn_update_dpp(0, __float_as_int(x), 0x111, 0xf, 0xf, false)); // row_shr:1
    x += t;
    t = __int_as_float(__builtin_amdgcn_update_dpp(0, __float_as_int(x), 0x112, 0xf, 0xf, false)); // row_shr:2
    x += t;
    t = __int_as_float(__builtin_amdgcn_update_dpp(0, __float_as_int(x), 0x114, 0xf, 0xf, false)); // row_shr:4
    x += t;
    t = __int_as_float(__builtin_amdgcn_update_dpp(0, __float_as_int(x), 0x118, 0xf, 0xf, false)); // row_shr:8
    x += t;
    t = __int_as_float(__builtin_amdgcn_update_dpp(0, __float_as_int(x), 0x142, 0xa, 0xf, false)); // row_bcast:15
    x += t;
    t = __int_as_float(__builtin_amdgcn_update_dpp(0, __float_as_int(x), 0x143, 0xc, 0xf, false)); // row_bcast:31
    x += t;
    return __int_as_float(__builtin_amdgcn_readlane(__float_as_int(x), 63));
}

// wave_shr:1 — lane i gets lane i-1's value (pure VALU)
__device__ __forceinline__ float dpp_shr1(float x) {
    return __int_as_float(__builtin_amdgcn_update_dpp(0, __float_as_int(x), 0x138, 0xf, 0xf, false));
}
// wave_shl:1 — lane i gets lane i+1's value (pure VALU)
__device__ __forceinline__ float dpp_shl1(float x) {
    return __int_as_float(__builtin_amdgcn_update_dpp(0, __float_as_int(x), 0x130, 0xf, 0xf, false));
}
__device__ __forceinline__ float readlane_f(float x, int l) {
    return __int_as_float(__builtin_amdgcn_readlane(__float_as_int(x), l));
}

// ---------------------------------------------------------------------------
// Kernel 1: Dykstra sparse-soft-topk on alpha (n=256) with ONE wave (64 lanes,
// 4 elements per lane), then dv[o] = y[0] * V[0,o].
// p = (sum(u)-k)/n is the SAME scalar for all elements -> scalar register.
// ---------------------------------------------------------------------------
__global__ __launch_bounds__(64) void prep_kernel(const float* __restrict__ alpha,
                                                  const float* __restrict__ V,
                                                  float* __restrict__ dv) {
    const int t = threadIdx.x;   // 0..63
    float y[4], q[4];
    float p = 0.0f;
#pragma unroll
    for (int j = 0; j < 4; ++j) {
        y[j] = alpha[t * 4 + j] / 0.01f;   // y0 = s / l
        q[j] = 0.0f;
    }

    for (int it = 0; it < NITER; ++it) {
        float u[4];
        float part = 0.0f;
#pragma unroll
        for (int j = 0; j < 4; ++j) {
            u[j] = y[j] + p;
            part += u[j];
        }
        const float S = wave_sum_dpp(part);                   // sum over all 256
        const float delta = (S - KTOP) * (1.0f / 256.0f);     // (sum(u)-k)/n
        p = delta;                                            // p = u - z (scalar)
#pragma unroll
        for (int j = 0; j < 4; ++j) {
            const float z = u[j] - delta;
            const float v = z + q[j];
            y[j] = fminf(fmaxf(v, 0.0f), 1.0f);               // clip to [0,1]
            q[j] = v - y[j];
        }
    }

    // only alpha_topk[0] matters: diag_vals[o] = y0 * V[0, o]
    const float y0 = readlane_f(y[0], 0);
#pragma unroll
    for (int j = 0; j < 4; ++j) {
        const int o = t * 4 + j;
        dv[o] = y0 * V[o];   // V row 0
    }
}

// ---------------------------------------------------------------------------
// Kernel 2: out[n,o,t] = dv[o]*(x[t-1]+x[t]+x[t+1]) + bias[o], zero-padded.
// Each wave owns 256 CONSECUTIVE float4 as 4 segments of 64:
//   v[s] = x4[c*256 + s*64 + lane]  -> every load/store instruction is
// 64x16B contiguous (full 64B lines, 4 outstanding loads per lane).
// Halos: DPP within a segment, v_readlane across segments, scalar loads only
// at lane 0/63 chunk edges. dv/bias are block-uniform -> scalar loads.
// nt stores keep the write-once output from evicting L3-resident x.
// ---------------------------------------------------------------------------
__global__ __launch_bounds__(256) void conv_kernel(const float* __restrict__ x,
                                                   const float* __restrict__ dv,
                                                   const float* __restrict__ bias,
                                                   f4* __restrict__ out4) {
    const int lane = threadIdx.x & 63;
    const int wid  = threadIdx.x >> 6;            // wave in block, 0..3
    const int w    = blockIdx.x * 4 + wid;        // global wave id
    const int row  = w >> 4;                      // 16 chunks of 256 f4 per row
    const int c    = w & 15;                      // chunk within row
    const int o    = row & (C - 1);               // channel (block-uniform)

    const float d = dv[o];
    const float b = bias[o];

    const float* __restrict__ xr = x + ((size_t)row << 14);  // row * LENGTH
    const f4* __restrict__ x4r = reinterpret_cast<const f4*>(xr);

    const int j0 = c * 256 + lane;
    f4 v[4];
#pragma unroll
    for (int s = 0; s < 4; ++s) v[s] = x4r[j0 + s * 64];

    // within-segment halos (pure VALU)
    float pw[4], nx[4];
#pragma unroll
    for (int s = 0; s < 4; ++s) {
        pw[s] = dpp_shr1(v[s].w);   // float before v[s].x
        nx[s] = dpp_shl1(v[s].x);   // float after  v[s].w
    }

    // cross-segment halos via SGPR broadcast (uniform values, cheap)
    const float first1 = readlane_f(v[1].x, 0);
    const float first2 = readlane_f(v[2].x, 0);
    const float first3 = readlane_f(v[3].x, 0);
    const float last0  = readlane_f(v[0].w, 63);
    const float last1  = readlane_f(v[1].w, 63);
    const float last2  = readlane_f(v[2].w, 63);
    if (lane == 63) {
        nx[0] = first1;
        nx[1] = first2;
        nx[2] = first3;
        nx[3] = (c < 15) ? xr[4 * j0 + 4 * 192 + 4] : 0.0f;  // next chunk / row end
    }
    if (lane == 0) {
        pw[1] = last0;
        pw[2] = last1;
        pw[3] = last2;
        pw[0] = (c > 0) ? xr[4 * j0 - 1] : 0.0f;             // prev chunk / row start
    }

    f4* __restrict__ o4r = out4 + ((size_t)row << 12);
#pragma unroll
    for (int s = 0; s < 4; ++s) {
        f4 r;
        r.x = fmaf(d, pw[s]  + v[s].x + v[s].y, b);
        r.y = fmaf(d, v[s].x + v[s].y + v[s].z, b);
        r.z = fmaf(d, v[s].y + v[s].z + v[s].w, b);
        r.w = fmaf(d, v[s].z + v[s].w + nx[s],  b);
        __builtin_nontemporal_store(r, &o4r[j0 + s * 64]);
    }
}

extern "C" void kernel_launch(void* const* d_in, const int* in_sizes, int n_in,
                              void* d_out, int out_size, void* d_ws, size_t ws_size,
                              hipStream_t stream) {
    const float* x     = (const float*)d_in[0];   // [8, 256, 16384]
    const float* V     = (const float*)d_in[1];   // [256, 256]
    const float* alpha = (const float*)d_in[2];   // [256]
    const float* bias  = (const float*)d_in[3];   // [256]
    float* out = (float*)d_out;                   // [8, 256, 16384]
    float* dv  = (float*)d_ws;                    // 256 floats scratch

    prep_kernel<<<1, 64, 0, stream>>>(alpha, V, dv);
    conv_kernel<<<NBLOCKS, 256, 0, stream>>>(x, dv, bias, (f4*)out);
}